// Round 5
// baseline (356.228 us; speedup 1.0000x reference)
//
#include <hip/hip_runtime.h>
#include <hip/hip_bf16.h>

#define B_SZ 8192
#define IH   2048
#define H_SZ 1024
#define BM   256            // rows per block
#define BK   64             // K per tile
#define NT   (IH / BK)      // 32 K-tiles
#define NI   (NT / 2)       // 16 iterations, 2 K-tiles each
#define DBUF 65536          // one dbuf: A [256][128B] + W [256][128B]
#define WOFF 32768          // W region offset inside a dbuf

typedef __attribute__((ext_vector_type(8))) short  short8;
typedef __attribute__((ext_vector_type(4))) float  floatx4;

static __device__ __forceinline__ ushort f2bf(float f) {
  union { float f; unsigned u; } v; v.f = f;
  unsigned u = v.u;
  u += 0x7fffu + ((u >> 16) & 1u);   // RNE
  return (ushort)(u >> 16);
}
static __device__ __forceinline__ float sigmoidf_(float x) {
  return 1.0f / (1.0f + __expf(-x));
}
static __device__ __forceinline__ float tanhf_(float x) {
  float ax = fabsf(x);
  float e = __expf(-2.0f * ax);
  float t = (1.0f - e) / (1.0f + e);
  return copysignf(t, x);
}
static __device__ __forceinline__ void gload_lds16(const void* gsrc, void* ldst) {
  __builtin_amdgcn_global_load_lds(
      (__attribute__((address_space(1))) const void*)gsrc,
      (__attribute__((address_space(3))) void*)ldst, 16, 0, 0);
}

// ---------------------------------------------------------------------------
// Pre-pass 1: W[k][n] fp32 -> Wt[g][n][k] bf16 (K-contiguous for MFMA B-frag)
// ---------------------------------------------------------------------------
__global__ __launch_bounds__(256) void convert_w_kernel(
    const float* __restrict__ Wf, const float* __restrict__ Wi,
    const float* __restrict__ Wo, const float* __restrict__ Wc,
    ushort* __restrict__ Wt) {
  __shared__ float tile[64][65];
  const int g  = blockIdx.z;
  const float* W = (g == 0) ? Wf : (g == 1) ? Wi : (g == 2) ? Wo : Wc;
  const int n0 = blockIdx.x * 64;
  const int k0 = blockIdx.y * 64;
  const int tid = threadIdx.x;
#pragma unroll
  for (int i = 0; i < 4; ++i) {
    int c = i * 256 + tid;
    int r = c >> 4, c4 = c & 15;
    float4 v = *(const float4*)(W + (size_t)(k0 + r) * H_SZ + n0 + c4 * 4);
    tile[r][c4 * 4 + 0] = v.x;
    tile[r][c4 * 4 + 1] = v.y;
    tile[r][c4 * 4 + 2] = v.z;
    tile[r][c4 * 4 + 3] = v.w;
  }
  __syncthreads();
  const int n  = tid >> 2;
  const int kc = (tid & 3) * 16;
  ushort o[16] __attribute__((aligned(16)));
#pragma unroll
  for (int e = 0; e < 16; ++e) o[e] = f2bf(tile[kc + e][n]);
  ushort* dst = Wt + ((size_t)g * H_SZ + n0 + n) * IH + k0 + kc;
  *(uint4*)(dst)     = *(uint4*)&o[0];
  *(uint4*)(dst + 8) = *(uint4*)&o[8];
}

// ---------------------------------------------------------------------------
// Pre-pass 2: A = [x | h_prev] fp32 -> Abf[8192][2048] bf16
// ---------------------------------------------------------------------------
__global__ __launch_bounds__(256) void convert_a_kernel(
    const float* __restrict__ x, const float* __restrict__ hp,
    ushort* __restrict__ Abf) {
  size_t idx = ((size_t)blockIdx.x * 256 + threadIdx.x) * 8;
  size_t row = idx >> 11;
  size_t col = idx & 2047;
  const float* src = (col < 1024) ? (x  + row * 1024 + col)
                                  : (hp + row * 1024 + (col - 1024));
  float4 v0 = *(const float4*)(src);
  float4 v1 = *(const float4*)(src + 4);
  ushort o[8] __attribute__((aligned(16)));
  o[0] = f2bf(v0.x); o[1] = f2bf(v0.y); o[2] = f2bf(v0.z); o[3] = f2bf(v0.w);
  o[4] = f2bf(v1.x); o[5] = f2bf(v1.y); o[6] = f2bf(v1.z); o[7] = f2bf(v1.w);
  *(uint4*)(Abf + idx) = *(uint4*)&o[0];
}

// ---------------------------------------------------------------------------
// Fused 4-gate GEMM + LSTM epilogue — 8-phase, reads pipelined ONE PHASE
// AHEAD of their consuming MFMA quadrant, counted lgkm waits (T4 on lgkm).
//
// Geometry as round 4: 256 rows x (4 gates x 64 cols), 8 waves (4M x 2N),
// wave tile 64 rows x 128 fused-cols, 64 MFMA/wave/K-tile.
// LDS: 2 dbufs x 64 KiB (A then W at +32768), row swizzle byte^=(row&7)<<4
// on pre-swizzled global source + on ds_read (both-sides, rule 21).
//
// Quadrants of a K-tile (per wave): q0={aF01,bF0-3} q1={aF23} q2={bF4-7}
// q3={} ; MFMA: q0->MFQ(0,0) q1->MFQ(1,0) q2->MFQ(0,1) q3->MFQ(1,1).
// Read-issue schedule (one phase ahead; d0'=next tile in dbuf0):
//   P4: d1.q0[12]  P5: d1.q1[4]  P6: d1.q2[8]  P8: d0'.q0[12]
//   P1: d0.q1[4]   P2: d0.q2[8]  (P3,P7: none)
// lgkm waits (in-flight after wait in parens):
//   P1: lgkm(4) retires q0[12]   (q1 flies)     MFQ(0,0)
//   P2: lgkm(8) retires q1[4]    (q2 flies)     MFQ(1,0)
//   P3: lgkm(0) retires q2[8]                   MFQ(0,1)
//   P4: lgkm(12) (d1.q0 flies)                  MFQ(1,1)
//   P5-P8 mirror with d1 / d0'.
// Stage slots (UNCHANGED from verified r4 ledger):
//   P1: d1.W1@2i+1  P2: d0.W0@2i+2  P3: d0.A0  P4: d0.A1  P5: d0.W1
//   P6: d1.W0@2i+3  P7: d1.A0  P8: d1.A1   (kt wraps &31 near end: dead data)
// vmcnt: VMC(4) end of P3 -> retires through this-P1 => d1 (prevP6,prevP7,
//   prevP8,thisP1) fully landed before P4 issues d1 reads. VMC(4) end of P7
//   -> retires through P5 => d0' (P2..P5) landed before P8 issues d0' reads.
// WAR: every staged region's readers lgkm-retired >=1 barrier before the
//   stage issue (checked per slot). Register overlap: per phase, the
//   issued-fragment set and the consumed-fragment set are disjoint.
// ---------------------------------------------------------------------------
__global__ __launch_bounds__(512, 2) void lstm_fused_kernel(
    const float* __restrict__ Cp, const ushort* __restrict__ Wt,
    const ushort* __restrict__ Abf,
    const float* __restrict__ bf_, const float* __restrict__ bi_,
    const float* __restrict__ bo_, const float* __restrict__ bc_,
    float* __restrict__ out) {
  __shared__ char lds[2 * DBUF];   // 128 KiB

  const int bid = blockIdx.x;
  const int wg  = (bid & 7) * 64 + (bid >> 3);   // bijective, 512 % 8 == 0
  const int b0  = (wg >> 4) * BM;                // 32 M-tiles
  const int n0g = (wg & 15) * 64;                // 16 N-tiles (64 cols/gate)

  const int tid = threadIdx.x;
  const int ln  = tid & 63;
  const int wv  = tid >> 6;
  const int wm  = wv >> 1, wn = wv & 1;

  floatx4 acc[4][8];
#pragma unroll
  for (int m = 0; m < 4; ++m)
#pragma unroll
    for (int j = 0; j < 8; ++j) acc[m][j] = {0.f, 0.f, 0.f, 0.f};

  // ---- per-thread read constants ----
  const int sw = (ln & 7) << 4;
  int kb[2];
  kb[0] = (((ln >> 4) << 4)) ^ sw;
  kb[1] = (64 + ((ln >> 4) << 4)) ^ sw;
  int arow[4], brow[8];
#pragma unroll
  for (int mf = 0; mf < 4; ++mf)
    arow[mf] = (wm * 64 + mf * 16 + (ln & 15)) * 128;
#pragma unroll
  for (int j = 0; j < 8; ++j) {
    int g = j >> 1, ns = j & 1;
    brow[j] = WOFF + (g * 64 + wn * 32 + ns * 16 + (ln & 15)) * 128;
  }

  // ---- per-thread stage constants ----
  const int    kcsw = ((tid & 7) * 16) ^ (((tid >> 3) & 7) << 4);
  const char*  AbfB = (const char*)Abf;
  const char*  WtB  = (const char*)Wt;
  size_t aoff[2];
#pragma unroll
  for (int i = 0; i < 2; ++i)
    aoff[i] = ((size_t)(b0 + i * 64 + (tid >> 3)) << 12) + kcsw;
  size_t woff[2][2];
#pragma unroll
  for (int h = 0; h < 2; ++h)
#pragma unroll
    for (int i = 0; i < 2; ++i) {
      int nrt  = h * 128 + i * 64 + (tid >> 3);
      int g    = nrt >> 6, nloc = nrt & 63;
      woff[h][i] = ((size_t)(g * H_SZ + n0g + nloc) << 12) + kcsw;
    }
  int dsto[2];
#pragma unroll
  for (int i = 0; i < 2; ++i) dsto[i] = (i * 512 + wv * 64) * 16;

#define STAGE_A(db, ktb, h)                                                   \
  do {                                                                        \
    gload_lds16(AbfB + aoff[0] + ((size_t)(h) << 19) + (ktb),                 \
                lds + (db) + (h) * 16384 + dsto[0]);                          \
    gload_lds16(AbfB + aoff[1] + ((size_t)(h) << 19) + (ktb),                 \
                lds + (db) + (h) * 16384 + dsto[1]);                          \
  } while (0)
#define STAGE_W(db, ktb, h)                                                   \
  do {                                                                        \
    gload_lds16(WtB + woff[h][0] + (ktb),                                     \
                lds + (db) + WOFF + (h) * 16384 + dsto[0]);                   \
    gload_lds16(WtB + woff[h][1] + (ktb),                                     \
                lds + (db) + WOFF + (h) * 16384 + dsto[1]);                   \
  } while (0)

  short8 aF[4][2];
  short8 bF[8][2];
#define RD_A(db, mf)                                                          \
  do {                                                                        \
    aF[mf][0] = *(const short8*)(lds + (db) + arow[mf] + kb[0]);              \
    aF[mf][1] = *(const short8*)(lds + (db) + arow[mf] + kb[1]);              \
  } while (0)
#define RD_B(db, j)                                                           \
  do {                                                                        \
    bF[j][0] = *(const short8*)(lds + (db) + brow[j] + kb[0]);                \
    bF[j][1] = *(const short8*)(lds + (db) + brow[j] + kb[1]);                \
  } while (0)
#define RDQ0(db)                                                              \
  do { RD_A(db, 0); RD_A(db, 1);                                              \
       RD_B(db, 0); RD_B(db, 1); RD_B(db, 2); RD_B(db, 3); } while (0)
#define RDQ1(db)  do { RD_A(db, 2); RD_A(db, 3); } while (0)
#define RDQ2(db)  do { RD_B(db, 4); RD_B(db, 5); RD_B(db, 6); RD_B(db, 7); } while (0)
#define MFQ(mh, jh)                                                           \
  do {                                                                        \
    __builtin_amdgcn_s_setprio(1);                                            \
    _Pragma("unroll")                                                         \
    for (int mf_ = 2 * (mh); mf_ < 2 * (mh) + 2; ++mf_)                       \
      _Pragma("unroll")                                                       \
      for (int j_ = 4 * (jh); j_ < 4 * (jh) + 4; ++j_) {                      \
        acc[mf_][j_] = __builtin_amdgcn_mfma_f32_16x16x32_bf16(               \
            aF[mf_][0], bF[j_][0], acc[mf_][j_], 0, 0, 0);                    \
        acc[mf_][j_] = __builtin_amdgcn_mfma_f32_16x16x32_bf16(               \
            aF[mf_][1], bF[j_][1], acc[mf_][j_], 0, 0, 0);                    \
      }                                                                       \
    __builtin_amdgcn_s_setprio(0);                                            \
  } while (0)
#define BAR   __builtin_amdgcn_s_barrier()
#define LGKM(n)                                                               \
  do {                                                                        \
    asm volatile("s_waitcnt lgkmcnt(" #n ")" ::: "memory");                   \
    __builtin_amdgcn_sched_barrier(0);                                        \
  } while (0)
#define VMC(n) asm volatile("s_waitcnt vmcnt(" #n ")" ::: "memory")

  // ---- prologue: stage tile0 (d0, 4 halves) + tile1 (d1: W0,A0,A1);
  //      vmcnt(6) retires d0's 8 loads; barrier; issue d0.q0 reads ----
  STAGE_W(0, 0, 0); STAGE_A(0, 0, 0); STAGE_A(0, 0, 1); STAGE_W(0, 0, 1);
  STAGE_W(DBUF, 128, 0); STAGE_A(DBUF, 128, 0); STAGE_A(DBUF, 128, 1);
  VMC(6);
  BAR;
  RDQ0(0);

#pragma unroll 1
  for (int it = 0; it < NI; ++it) {
    const int kt1b  = (2 * it + 1) * 128;
    const int ktn0b = ((2 * it + 2) & 31) * 128;
    const int ktn1b = ((2 * it + 3) & 31) * 128;
    // P1: issue d0.q1; stage d1.W1@2i+1; consume d0.q0
    RDQ1(0); STAGE_W(DBUF, kt1b, 1);
    BAR; LGKM(4);  MFQ(0, 0); BAR;
    // P2: issue d0.q2; stage d0.W0@2i+2; consume d0.q1
    RDQ2(0); STAGE_W(0, ktn0b, 0);
    BAR; LGKM(8);  MFQ(1, 0); BAR;
    // P3: stage d0.A0; consume d0.q2; vmcnt(4) => d1 fully landed
    STAGE_A(0, ktn0b, 0);
    BAR; LGKM(0);  MFQ(0, 1); VMC(4); BAR;
    // P4: issue d1.q0; stage d0.A1; consume d0.q3
    RDQ0(DBUF); STAGE_A(0, ktn0b, 1);
    BAR; LGKM(12); MFQ(1, 1); BAR;
    // P5: issue d1.q1; stage d0.W1; consume d1.q0
    RDQ1(DBUF); STAGE_W(0, ktn0b, 1);
    BAR; LGKM(4);  MFQ(0, 0); BAR;
    // P6: issue d1.q2; stage d1.W0@2i+3; consume d1.q1
    RDQ2(DBUF); STAGE_W(DBUF, ktn1b, 0);
    BAR; LGKM(8);  MFQ(1, 0); BAR;
    // P7: stage d1.A0; consume d1.q2; vmcnt(4) => d0(next) fully landed
    STAGE_A(DBUF, ktn1b, 0);
    BAR; LGKM(0);  MFQ(0, 1); VMC(4); BAR;
    // P8: issue d0'.q0; stage d1.A1; consume d1.q3
    RDQ0(0); STAGE_A(DBUF, ktn1b, 1);
    BAR; LGKM(12); MFQ(1, 1); BAR;
  }

  // ---- epilogue: gate g at acc[mf][2g+ns]; same lane/reg across gates ----
  const int colq = ln & 15;
  const int rq   = ln >> 4;
  float* outh = out;
  float* outC = out + (size_t)B_SZ * H_SZ;
#pragma unroll
  for (int mf = 0; mf < 4; ++mf) {
#pragma unroll
    for (int ns = 0; ns < 2; ++ns) {
      int n = n0g + wn * 32 + ns * 16 + colq;
      float vbf = bf_[n], vbi = bi_[n], vbo = bo_[n], vbc = bc_[n];
#pragma unroll
      for (int r = 0; r < 4; ++r) {
        int row = b0 + wm * 64 + mf * 16 + rq * 4 + r;
        float fg = sigmoidf_(acc[mf][0 + ns][r] + vbf);
        float ig = sigmoidf_(acc[mf][2 + ns][r] + vbi);
        float og = sigmoidf_(acc[mf][4 + ns][r] + vbo);
        float cg = tanhf_  (acc[mf][6 + ns][r] + vbc);
        float cp = Cp[(size_t)row * H_SZ + n];
        float Ct = fg * cp + ig * cg;
        float ht = og * tanhf_(Ct);
        outh[(size_t)row * H_SZ + n] = ht;
        outC[(size_t)row * H_SZ + n] = Ct;
      }
    }
  }
#undef STAGE_A
#undef STAGE_W
#undef RD_A
#undef RD_B
#undef RDQ0
#undef RDQ1
#undef RDQ2
#undef MFQ
#undef BAR
#undef LGKM
#undef VMC
}

extern "C" void kernel_launch(void* const* d_in, const int* in_sizes, int n_in,
                              void* d_out, int out_size, void* d_ws, size_t ws_size,
                              hipStream_t stream) {
  const float* x  = (const float*)d_in[0];
  const float* hp = (const float*)d_in[1];
  const float* Cp = (const float*)d_in[2];
  const float* Wf = (const float*)d_in[3];
  const float* bf = (const float*)d_in[4];
  const float* Wi = (const float*)d_in[5];
  const float* bi = (const float*)d_in[6];
  const float* Wc = (const float*)d_in[7];
  const float* bc = (const float*)d_in[8];
  const float* Wo = (const float*)d_in[9];
  const float* bo = (const float*)d_in[10];

  ushort* Wt  = (ushort*)d_ws;                           // 16 MiB
  ushort* Abf = (ushort*)((char*)d_ws + (16u << 20));    // 32 MiB

  dim3 gridT(16, 32, 4);
  convert_w_kernel<<<gridT, 256, 0, stream>>>(Wf, Wi, Wo, Wc, Wt);
  convert_a_kernel<<<8192, 256, 0, stream>>>(x, hp, Abf);

  lstm_fused_kernel<<<512, 512, 0, stream>>>(Cp, Wt, Abf,
                                             bf, bi, bo, bc, (float*)d_out);
}

// Round 6
// 161.571 us; speedup vs baseline: 2.2048x; 2.2048x over previous
//
#include <hip/hip_runtime.h>
#include <hip/hip_bf16.h>

#define B_SZ 8192
#define IH   2048
#define H_SZ 1024
#define BM   256            // rows per block
#define BK   64             // K per tile
#define NT   (IH / BK)      // 32 K-tiles
#define NI   (NT / 2)       // 16 iterations, 2 K-tiles each
#define DBUF 65536          // one dbuf: A [256][128B] + W [256][128B]
#define WOFF 32768          // W region offset inside a dbuf

typedef __attribute__((ext_vector_type(8))) short  short8;
typedef __attribute__((ext_vector_type(4))) float  floatx4;

static __device__ __forceinline__ ushort f2bf(float f) {
  union { float f; unsigned u; } v; v.f = f;
  unsigned u = v.u;
  u += 0x7fffu + ((u >> 16) & 1u);   // RNE
  return (ushort)(u >> 16);
}
static __device__ __forceinline__ float sigmoidf_(float x) {
  return 1.0f / (1.0f + __expf(-x));
}
static __device__ __forceinline__ float tanhf_(float x) {
  float ax = fabsf(x);
  float e = __expf(-2.0f * ax);
  float t = (1.0f - e) / (1.0f + e);
  return copysignf(t, x);
}
static __device__ __forceinline__ void gload_lds16(const void* gsrc, void* ldst) {
  __builtin_amdgcn_global_load_lds(
      (__attribute__((address_space(1))) const void*)gsrc,
      (__attribute__((address_space(3))) void*)ldst, 16, 0, 0);
}

// ---------------------------------------------------------------------------
// Pre-pass 1: W[k][n] fp32 -> Wt[g][n][k] bf16 (K-contiguous for MFMA B-frag)
// ---------------------------------------------------------------------------
__global__ __launch_bounds__(256) void convert_w_kernel(
    const float* __restrict__ Wf, const float* __restrict__ Wi,
    const float* __restrict__ Wo, const float* __restrict__ Wc,
    ushort* __restrict__ Wt) {
  __shared__ float tile[64][65];
  const int g  = blockIdx.z;
  const float* W = (g == 0) ? Wf : (g == 1) ? Wi : (g == 2) ? Wo : Wc;
  const int n0 = blockIdx.x * 64;
  const int k0 = blockIdx.y * 64;
  const int tid = threadIdx.x;
#pragma unroll
  for (int i = 0; i < 4; ++i) {
    int c = i * 256 + tid;
    int r = c >> 4, c4 = c & 15;
    float4 v = *(const float4*)(W + (size_t)(k0 + r) * H_SZ + n0 + c4 * 4);
    tile[r][c4 * 4 + 0] = v.x;
    tile[r][c4 * 4 + 1] = v.y;
    tile[r][c4 * 4 + 2] = v.z;
    tile[r][c4 * 4 + 3] = v.w;
  }
  __syncthreads();
  const int n  = tid >> 2;
  const int kc = (tid & 3) * 16;
  ushort o[16] __attribute__((aligned(16)));
#pragma unroll
  for (int e = 0; e < 16; ++e) o[e] = f2bf(tile[kc + e][n]);
  ushort* dst = Wt + ((size_t)g * H_SZ + n0 + n) * IH + k0 + kc;
  *(uint4*)(dst)     = *(uint4*)&o[0];
  *(uint4*)(dst + 8) = *(uint4*)&o[8];
}

// ---------------------------------------------------------------------------
// Pre-pass 2: A = [x | h_prev] fp32 -> Abf[8192][2048] bf16
// ---------------------------------------------------------------------------
__global__ __launch_bounds__(256) void convert_a_kernel(
    const float* __restrict__ x, const float* __restrict__ hp,
    ushort* __restrict__ Abf) {
  size_t idx = ((size_t)blockIdx.x * 256 + threadIdx.x) * 8;
  size_t row = idx >> 11;
  size_t col = idx & 2047;
  const float* src = (col < 1024) ? (x  + row * 1024 + col)
                                  : (hp + row * 1024 + (col - 1024));
  float4 v0 = *(const float4*)(src);
  float4 v1 = *(const float4*)(src + 4);
  ushort o[8] __attribute__((aligned(16)));
  o[0] = f2bf(v0.x); o[1] = f2bf(v0.y); o[2] = f2bf(v0.z); o[3] = f2bf(v0.w);
  o[4] = f2bf(v1.x); o[5] = f2bf(v1.y); o[6] = f2bf(v1.z); o[7] = f2bf(v1.w);
  *(uint4*)(Abf + idx) = *(uint4*)&o[0];
}

// ---------------------------------------------------------------------------
// Fused 4-gate GEMM + LSTM epilogue — r4 8-phase skeleton, but NO explicit
// lgkmcnt(0)/sched_barrier before the MFMA clusters: the compiler emits
// fine-grained counted lgkmcnt between ds_read and consuming MFMA, so the
// LDS drain overlaps the MFMA cluster instead of fully serializing (m97
// note; m141: explicit order-pinning regresses).
//
// Correctness without explicit lgkm: every fragment loaded in phase p is
// consumed by an MFMA in phase p => its ds_read retires before the post-MFQ
// barrier of p (hw: compiler-inserted wait precedes the consuming MFMA).
// Stage-overwrite of any region is issued >=1 barrier after its readers'
// phase (r4 WAR ledger unchanged). RAW: VMC6 at P4/P8 retires stages
// through P1/P5 => the dbuf read in P5/next-P1 is fully landed. The VMC6
// asm has a memory clobber: RDQ/STAGE memory ops cannot cross it.
//
// Stage slots (verified r4 ledger):
//   P1: d1.W1@2i+1  P2: d0.W0@2i+2  P3: d0.A0  P4: d0.A1  P5: d0.W1
//   P6: d1.W0@2i+3  P7: d1.A0  P8: d1.A1   (kt wraps &31 near end: dead data)
// ---------------------------------------------------------------------------
__global__ __launch_bounds__(512, 2) void lstm_fused_kernel(
    const float* __restrict__ Cp, const ushort* __restrict__ Wt,
    const ushort* __restrict__ Abf,
    const float* __restrict__ bf_, const float* __restrict__ bi_,
    const float* __restrict__ bo_, const float* __restrict__ bc_,
    float* __restrict__ out) {
  __shared__ char lds[2 * DBUF];   // 128 KiB

  const int bid = blockIdx.x;
  const int wg  = (bid & 7) * 64 + (bid >> 3);   // bijective, 512 % 8 == 0
  const int b0  = (wg >> 4) * BM;                // 32 M-tiles
  const int n0g = (wg & 15) * 64;                // 16 N-tiles (64 cols/gate)

  const int tid = threadIdx.x;
  const int ln  = tid & 63;
  const int wv  = tid >> 6;
  const int wm  = wv >> 1, wn = wv & 1;

  floatx4 acc[4][8];
#pragma unroll
  for (int m = 0; m < 4; ++m)
#pragma unroll
    for (int j = 0; j < 8; ++j) acc[m][j] = {0.f, 0.f, 0.f, 0.f};

  // ---- per-thread read constants ----
  const int sw = (ln & 7) << 4;
  int kb[2];
  kb[0] = (((ln >> 4) << 4)) ^ sw;
  kb[1] = (64 + ((ln >> 4) << 4)) ^ sw;
  int arow[4], brow[8];
#pragma unroll
  for (int mf = 0; mf < 4; ++mf)
    arow[mf] = (wm * 64 + mf * 16 + (ln & 15)) * 128;
#pragma unroll
  for (int j = 0; j < 8; ++j) {
    int g = j >> 1, ns = j & 1;
    brow[j] = WOFF + (g * 64 + wn * 32 + ns * 16 + (ln & 15)) * 128;
  }

  // ---- per-thread stage constants ----
  const int    kcsw = ((tid & 7) * 16) ^ (((tid >> 3) & 7) << 4);
  const char*  AbfB = (const char*)Abf;
  const char*  WtB  = (const char*)Wt;
  size_t aoff[2];
#pragma unroll
  for (int i = 0; i < 2; ++i)
    aoff[i] = ((size_t)(b0 + i * 64 + (tid >> 3)) << 12) + kcsw;
  size_t woff[2][2];
#pragma unroll
  for (int h = 0; h < 2; ++h)
#pragma unroll
    for (int i = 0; i < 2; ++i) {
      int nrt  = h * 128 + i * 64 + (tid >> 3);
      int g    = nrt >> 6, nloc = nrt & 63;
      woff[h][i] = ((size_t)(g * H_SZ + n0g + nloc) << 12) + kcsw;
    }
  int dsto[2];
#pragma unroll
  for (int i = 0; i < 2; ++i) dsto[i] = (i * 512 + wv * 64) * 16;

#define STAGE_A(db, ktb, h)                                                   \
  do {                                                                        \
    gload_lds16(AbfB + aoff[0] + ((size_t)(h) << 19) + (ktb),                 \
                lds + (db) + (h) * 16384 + dsto[0]);                          \
    gload_lds16(AbfB + aoff[1] + ((size_t)(h) << 19) + (ktb),                 \
                lds + (db) + (h) * 16384 + dsto[1]);                          \
  } while (0)
#define STAGE_W(db, ktb, h)                                                   \
  do {                                                                        \
    gload_lds16(WtB + woff[h][0] + (ktb),                                     \
                lds + (db) + WOFF + (h) * 16384 + dsto[0]);                   \
    gload_lds16(WtB + woff[h][1] + (ktb),                                     \
                lds + (db) + WOFF + (h) * 16384 + dsto[1]);                   \
  } while (0)

  short8 aF[4][2];
  short8 bF[8][2];
#define RD_A(db, mf)                                                          \
  do {                                                                        \
    aF[mf][0] = *(const short8*)(lds + (db) + arow[mf] + kb[0]);              \
    aF[mf][1] = *(const short8*)(lds + (db) + arow[mf] + kb[1]);              \
  } while (0)
#define RD_B(db, j)                                                           \
  do {                                                                        \
    bF[j][0] = *(const short8*)(lds + (db) + brow[j] + kb[0]);                \
    bF[j][1] = *(const short8*)(lds + (db) + brow[j] + kb[1]);                \
  } while (0)
// k-outer / j-inner: consecutive MFMAs never share an accumulator.
#define MFQ(mh, jh)                                                           \
  do {                                                                        \
    __builtin_amdgcn_s_setprio(1);                                            \
    _Pragma("unroll")                                                         \
    for (int k_ = 0; k_ < 2; ++k_)                                            \
      _Pragma("unroll")                                                       \
      for (int mf_ = 2 * (mh); mf_ < 2 * (mh) + 2; ++mf_)                     \
        _Pragma("unroll")                                                     \
        for (int j_ = 4 * (jh); j_ < 4 * (jh) + 4; ++j_)                      \
          acc[mf_][j_] = __builtin_amdgcn_mfma_f32_16x16x32_bf16(             \
              aF[mf_][k_], bF[j_][k_], acc[mf_][j_], 0, 0, 0);                \
    __builtin_amdgcn_s_setprio(0);                                            \
  } while (0)
#define BAR   __builtin_amdgcn_s_barrier()
#define VMC6  asm volatile("s_waitcnt vmcnt(6)" ::: "memory")

  // ---- prologue ----
  STAGE_W(0, 0, 0); STAGE_A(0, 0, 0); STAGE_A(0, 0, 1); STAGE_W(0, 0, 1);
  STAGE_W(DBUF, 128, 0); STAGE_A(DBUF, 128, 0); STAGE_A(DBUF, 128, 1);
  VMC6;
  BAR;

#pragma unroll 1
  for (int it = 0; it < NI; ++it) {
    const int kt1b  = (2 * it + 1) * 128;
    const int ktn0b = ((2 * it + 2) & 31) * 128;
    const int ktn1b = ((2 * it + 3) & 31) * 128;
    // P1
    RD_A(0, 0); RD_A(0, 1);
    RD_B(0, 0); RD_B(0, 1); RD_B(0, 2); RD_B(0, 3);
    STAGE_W(DBUF, kt1b, 1);
    BAR; MFQ(0, 0); BAR;
    // P2
    RD_A(0, 2); RD_A(0, 3);
    STAGE_W(0, ktn0b, 0);
    BAR; MFQ(1, 0); BAR;
    // P3
    RD_B(0, 4); RD_B(0, 5); RD_B(0, 6); RD_B(0, 7);
    STAGE_A(0, ktn0b, 0);
    BAR; MFQ(0, 1); BAR;
    // P4
    STAGE_A(0, ktn0b, 1);
    BAR; MFQ(1, 1);
    VMC6; BAR;
    // P5
    RD_A(DBUF, 0); RD_A(DBUF, 1);
    RD_B(DBUF, 0); RD_B(DBUF, 1); RD_B(DBUF, 2); RD_B(DBUF, 3);
    STAGE_W(0, ktn0b, 1);
    BAR; MFQ(0, 0); BAR;
    // P6
    RD_A(DBUF, 2); RD_A(DBUF, 3);
    STAGE_W(DBUF, ktn1b, 0);
    BAR; MFQ(1, 0); BAR;
    // P7
    RD_B(DBUF, 4); RD_B(DBUF, 5); RD_B(DBUF, 6); RD_B(DBUF, 7);
    STAGE_A(DBUF, ktn1b, 0);
    BAR; MFQ(0, 1); BAR;
    // P8
    STAGE_A(DBUF, ktn1b, 1);
    BAR; MFQ(1, 1);
    VMC6; BAR;
  }

  // ---- epilogue: gate g at acc[mf][2g+ns]; same lane/reg across gates ----
  const int colq = ln & 15;
  const int rq   = ln >> 4;
  float* outh = out;
  float* outC = out + (size_t)B_SZ * H_SZ;
#pragma unroll
  for (int mf = 0; mf < 4; ++mf) {
#pragma unroll
    for (int ns = 0; ns < 2; ++ns) {
      int n = n0g + wn * 32 + ns * 16 + colq;
      float vbf = bf_[n], vbi = bi_[n], vbo = bo_[n], vbc = bc_[n];
#pragma unroll
      for (int r = 0; r < 4; ++r) {
        int row = b0 + wm * 64 + mf * 16 + rq * 4 + r;
        float fg = sigmoidf_(acc[mf][0 + ns][r] + vbf);
        float ig = sigmoidf_(acc[mf][2 + ns][r] + vbi);
        float og = sigmoidf_(acc[mf][4 + ns][r] + vbo);
        float cg = tanhf_  (acc[mf][6 + ns][r] + vbc);
        float cp = Cp[(size_t)row * H_SZ + n];
        float Ct = fg * cp + ig * cg;
        float ht = og * tanhf_(Ct);
        outh[(size_t)row * H_SZ + n] = ht;
        outC[(size_t)row * H_SZ + n] = Ct;
      }
    }
  }
#undef STAGE_A
#undef STAGE_W
#undef RD_A
#undef RD_B
#undef MFQ
#undef BAR
#undef VMC6
}

extern "C" void kernel_launch(void* const* d_in, const int* in_sizes, int n_in,
                              void* d_out, int out_size, void* d_ws, size_t ws_size,
                              hipStream_t stream) {
  const float* x  = (const float*)d_in[0];
  const float* hp = (const float*)d_in[1];
  const float* Cp = (const float*)d_in[2];
  const float* Wf = (const float*)d_in[3];
  const float* bf = (const float*)d_in[4];
  const float* Wi = (const float*)d_in[5];
  const float* bi = (const float*)d_in[6];
  const float* Wc = (const float*)d_in[7];
  const float* bc = (const float*)d_in[8];
  const float* Wo = (const float*)d_in[9];
  const float* bo = (const float*)d_in[10];

  ushort* Wt  = (ushort*)d_ws;                           // 16 MiB
  ushort* Abf = (ushort*)((char*)d_ws + (16u << 20));    // 32 MiB

  dim3 gridT(16, 32, 4);
  convert_w_kernel<<<gridT, 256, 0, stream>>>(Wf, Wi, Wo, Wc, Wt);
  convert_a_kernel<<<8192, 256, 0, stream>>>(x, hp, Abf);

  lstm_fused_kernel<<<512, 512, 0, stream>>>(Cp, Wt, Abf,
                                             bf, bi, bo, bc, (float*)d_out);
}

// Round 7
// 158.500 us; speedup vs baseline: 2.2475x; 1.0194x over previous
//
#include <hip/hip_runtime.h>
#include <hip/hip_bf16.h>

#define B_SZ 8192
#define IH   2048
#define H_SZ 1024
#define BM   256            // rows per block
#define BK   64             // K per tile
#define NT   (IH / BK)      // 32 K-tiles
#define NI   (NT / 2)       // 16 iterations, 2 K-tiles each
#define DBUF 65536          // one dbuf: A [256][128B] + W [256][128B]
#define WOFF 32768          // W region offset inside a dbuf

typedef __attribute__((ext_vector_type(8))) short  short8;
typedef __attribute__((ext_vector_type(4))) float  floatx4;

static __device__ __forceinline__ ushort f2bf(float f) {
  union { float f; unsigned u; } v; v.f = f;
  unsigned u = v.u;
  u += 0x7fffu + ((u >> 16) & 1u);   // RNE
  return (ushort)(u >> 16);
}
static __device__ __forceinline__ float sigmoidf_(float x) {
  return 1.0f / (1.0f + __expf(-x));
}
static __device__ __forceinline__ float tanhf_(float x) {
  float ax = fabsf(x);
  float e = __expf(-2.0f * ax);
  float t = (1.0f - e) / (1.0f + e);
  return copysignf(t, x);
}
static __device__ __forceinline__ void gload_lds16(const void* gsrc, void* ldst) {
  __builtin_amdgcn_global_load_lds(
      (__attribute__((address_space(1))) const void*)gsrc,
      (__attribute__((address_space(3))) void*)ldst, 16, 0, 0);
}

// ---------------------------------------------------------------------------
// Pre-pass 1: W[k][n] fp32 -> Wt[g][n][k] bf16 (K-contiguous for MFMA B-frag)
// ---------------------------------------------------------------------------
__global__ __launch_bounds__(256) void convert_w_kernel(
    const float* __restrict__ Wf, const float* __restrict__ Wi,
    const float* __restrict__ Wo, const float* __restrict__ Wc,
    ushort* __restrict__ Wt) {
  __shared__ float tile[64][65];
  const int g  = blockIdx.z;
  const float* W = (g == 0) ? Wf : (g == 1) ? Wi : (g == 2) ? Wo : Wc;
  const int n0 = blockIdx.x * 64;
  const int k0 = blockIdx.y * 64;
  const int tid = threadIdx.x;
#pragma unroll
  for (int i = 0; i < 4; ++i) {
    int c = i * 256 + tid;
    int r = c >> 4, c4 = c & 15;
    float4 v = *(const float4*)(W + (size_t)(k0 + r) * H_SZ + n0 + c4 * 4);
    tile[r][c4 * 4 + 0] = v.x;
    tile[r][c4 * 4 + 1] = v.y;
    tile[r][c4 * 4 + 2] = v.z;
    tile[r][c4 * 4 + 3] = v.w;
  }
  __syncthreads();
  const int n  = tid >> 2;
  const int kc = (tid & 3) * 16;
  ushort o[16] __attribute__((aligned(16)));
#pragma unroll
  for (int e = 0; e < 16; ++e) o[e] = f2bf(tile[kc + e][n]);
  ushort* dst = Wt + ((size_t)g * H_SZ + n0 + n) * IH + k0 + kc;
  *(uint4*)(dst)     = *(uint4*)&o[0];
  *(uint4*)(dst + 8) = *(uint4*)&o[8];
}

// ---------------------------------------------------------------------------
// Pre-pass 2: A = [x | h_prev] fp32 -> Abf[8192][2048] bf16
// ---------------------------------------------------------------------------
__global__ __launch_bounds__(256) void convert_a_kernel(
    const float* __restrict__ x, const float* __restrict__ hp,
    ushort* __restrict__ Abf) {
  size_t idx = ((size_t)blockIdx.x * 256 + threadIdx.x) * 8;
  size_t row = idx >> 11;
  size_t col = idx & 2047;
  const float* src = (col < 1024) ? (x  + row * 1024 + col)
                                  : (hp + row * 1024 + (col - 1024));
  float4 v0 = *(const float4*)(src);
  float4 v1 = *(const float4*)(src + 4);
  ushort o[8] __attribute__((aligned(16)));
  o[0] = f2bf(v0.x); o[1] = f2bf(v0.y); o[2] = f2bf(v0.z); o[3] = f2bf(v0.w);
  o[4] = f2bf(v1.x); o[5] = f2bf(v1.y); o[6] = f2bf(v1.z); o[7] = f2bf(v1.w);
  *(uint4*)(Abf + idx) = *(uint4*)&o[0];
}

// ---------------------------------------------------------------------------
// Fused 4-gate GEMM + LSTM epilogue — r6 8-phase skeleton (verified ledger),
// with ds_read addressing collapsed to 8 PINNED int bases + compile-time
// immediate offsets (fold into ds_read offset:). Goal: eliminate the
// per-phase address rematerialization / acc shuttling seen as VALUBusy 28%
// at the 256-unified-VGPR/wave cap.
//
// Base byte-offsets (per dbuf d, k-half k):
//   aB[d][k] = d*DBUF + (wm*64 + (ln&15))*128 + kb[k]
//   bB[d][k] = d*DBUF + WOFF + (wn*32 + (ln&15))*128 + kb[k]
// Reads (all deltas literal):
//   aF[mf][k] = lds[aB[d][k] + mf*2048]
//   bF[j][k]  = lds[bB[d][k] + (j>>1)*8192 + (j&1)*2048]
// Stage slots / vmcnt(6) / WAR-RAW ledger: unchanged from r4 (verified).
// ---------------------------------------------------------------------------
__global__ __launch_bounds__(512, 2) void lstm_fused_kernel(
    const float* __restrict__ Cp, const ushort* __restrict__ Wt,
    const ushort* __restrict__ Abf,
    const float* __restrict__ bf_, const float* __restrict__ bi_,
    const float* __restrict__ bo_, const float* __restrict__ bc_,
    float* __restrict__ out) {
  __shared__ char lds[2 * DBUF];   // 128 KiB

  const int bid = blockIdx.x;
  const int wg  = (bid & 7) * 64 + (bid >> 3);   // bijective, 512 % 8 == 0
  const int b0  = (wg >> 4) * BM;                // 32 M-tiles
  const int n0g = (wg & 15) * 64;                // 16 N-tiles (64 cols/gate)

  const int tid = threadIdx.x;
  const int ln  = tid & 63;
  const int wv  = tid >> 6;
  const int wm  = wv >> 1, wn = wv & 1;

  floatx4 acc[4][8];
#pragma unroll
  for (int m = 0; m < 4; ++m)
#pragma unroll
    for (int j = 0; j < 8; ++j) acc[m][j] = {0.f, 0.f, 0.f, 0.f};

  // ---- 8 pinned read bases ----
  const int sw  = (ln & 7) << 4;
  const int kb0 = (((ln >> 4) << 4)) ^ sw;
  const int kb1 = (64 + ((ln >> 4) << 4)) ^ sw;
  const int aR  = (wm * 64 + (ln & 15)) * 128;
  const int bR  = WOFF + (wn * 32 + (ln & 15)) * 128;
  int aB0[2], aB1[2], bB0[2], bB1[2];
#pragma unroll
  for (int d = 0; d < 2; ++d) {
    aB0[d] = d * DBUF + aR + kb0;  aB1[d] = d * DBUF + aR + kb1;
    bB0[d] = d * DBUF + bR + kb0;  bB1[d] = d * DBUF + bR + kb1;
  }

  // ---- per-thread stage constants ----
  const int    kcsw = ((tid & 7) * 16) ^ (((tid >> 3) & 7) << 4);
  const char*  AbfB = (const char*)Abf;
  const char*  WtB  = (const char*)Wt;
  size_t aoff[2];
#pragma unroll
  for (int i = 0; i < 2; ++i)
    aoff[i] = ((size_t)(b0 + i * 64 + (tid >> 3)) << 12) + kcsw;
  size_t woff[2][2];
#pragma unroll
  for (int h = 0; h < 2; ++h)
#pragma unroll
    for (int i = 0; i < 2; ++i) {
      int nrt  = h * 128 + i * 64 + (tid >> 3);
      int g    = nrt >> 6, nloc = nrt & 63;
      woff[h][i] = ((size_t)(g * H_SZ + n0g + nloc) << 12) + kcsw;
    }
  int dsto[2];
#pragma unroll
  for (int i = 0; i < 2; ++i) dsto[i] = (i * 512 + wv * 64) * 16;

#define STAGE_A(db, ktb, h)                                                   \
  do {                                                                        \
    gload_lds16(AbfB + aoff[0] + ((size_t)(h) << 19) + (ktb),                 \
                lds + (db) + (h) * 16384 + dsto[0]);                          \
    gload_lds16(AbfB + aoff[1] + ((size_t)(h) << 19) + (ktb),                 \
                lds + (db) + (h) * 16384 + dsto[1]);                          \
  } while (0)
#define STAGE_W(db, ktb, h)                                                   \
  do {                                                                        \
    gload_lds16(WtB + woff[h][0] + (ktb),                                     \
                lds + (db) + WOFF + (h) * 16384 + dsto[0]);                   \
    gload_lds16(WtB + woff[h][1] + (ktb),                                     \
                lds + (db) + WOFF + (h) * 16384 + dsto[1]);                   \
  } while (0)

  short8 aF[4][2];
  short8 bF[8][2];
#define RD_A(dbi, mf)                                                         \
  do {                                                                        \
    aF[mf][0] = *(const short8*)(lds + aB0[dbi] + (mf) * 2048);               \
    aF[mf][1] = *(const short8*)(lds + aB1[dbi] + (mf) * 2048);               \
  } while (0)
#define RD_B(dbi, j)                                                          \
  do {                                                                        \
    bF[j][0] = *(const short8*)(lds + bB0[dbi] + ((j) >> 1) * 8192 +          \
                                ((j) & 1) * 2048);                            \
    bF[j][1] = *(const short8*)(lds + bB1[dbi] + ((j) >> 1) * 8192 +          \
                                ((j) & 1) * 2048);                            \
  } while (0)
// k-outer / j-inner: consecutive MFMAs never share an accumulator.
#define MFQ(mh, jh)                                                           \
  do {                                                                        \
    __builtin_amdgcn_s_setprio(1);                                            \
    _Pragma("unroll")                                                         \
    for (int k_ = 0; k_ < 2; ++k_)                                            \
      _Pragma("unroll")                                                       \
      for (int mf_ = 2 * (mh); mf_ < 2 * (mh) + 2; ++mf_)                     \
        _Pragma("unroll")                                                     \
        for (int j_ = 4 * (jh); j_ < 4 * (jh) + 4; ++j_)                      \
          acc[mf_][j_] = __builtin_amdgcn_mfma_f32_16x16x32_bf16(             \
              aF[mf_][k_], bF[j_][k_], acc[mf_][j_], 0, 0, 0);                \
    __builtin_amdgcn_s_setprio(0);                                            \
  } while (0)
#define BAR   __builtin_amdgcn_s_barrier()
#define VMC6  asm volatile("s_waitcnt vmcnt(6)" ::: "memory")

  // ---- prologue ----
  STAGE_W(0, 0, 0); STAGE_A(0, 0, 0); STAGE_A(0, 0, 1); STAGE_W(0, 0, 1);
  STAGE_W(DBUF, 128, 0); STAGE_A(DBUF, 128, 0); STAGE_A(DBUF, 128, 1);
  VMC6;
  BAR;

#pragma unroll 1
  for (int it = 0; it < NI; ++it) {
    const int kt1b  = (2 * it + 1) * 128;
    const int ktn0b = ((2 * it + 2) & 31) * 128;
    const int ktn1b = ((2 * it + 3) & 31) * 128;
    // P1
    RD_A(0, 0); RD_A(0, 1);
    RD_B(0, 0); RD_B(0, 1); RD_B(0, 2); RD_B(0, 3);
    STAGE_W(DBUF, kt1b, 1);
    BAR; MFQ(0, 0); BAR;
    // P2
    RD_A(0, 2); RD_A(0, 3);
    STAGE_W(0, ktn0b, 0);
    BAR; MFQ(1, 0); BAR;
    // P3
    RD_B(0, 4); RD_B(0, 5); RD_B(0, 6); RD_B(0, 7);
    STAGE_A(0, ktn0b, 0);
    BAR; MFQ(0, 1); BAR;
    // P4
    STAGE_A(0, ktn0b, 1);
    BAR; MFQ(1, 1);
    VMC6; BAR;
    // P5
    RD_A(1, 0); RD_A(1, 1);
    RD_B(1, 0); RD_B(1, 1); RD_B(1, 2); RD_B(1, 3);
    STAGE_W(0, ktn0b, 1);
    BAR; MFQ(0, 0); BAR;
    // P6
    RD_A(1, 2); RD_A(1, 3);
    STAGE_W(DBUF, ktn1b, 0);
    BAR; MFQ(1, 0); BAR;
    // P7
    RD_B(1, 4); RD_B(1, 5); RD_B(1, 6); RD_B(1, 7);
    STAGE_A(DBUF, ktn1b, 0);
    BAR; MFQ(0, 1); BAR;
    // P8
    STAGE_A(DBUF, ktn1b, 1);
    BAR; MFQ(1, 1);
    VMC6; BAR;
  }

  // ---- epilogue: gate g at acc[mf][2g+ns]; same lane/reg across gates ----
  const int colq = ln & 15;
  const int rq   = ln >> 4;
  float* outh = out;
  float* outC = out + (size_t)B_SZ * H_SZ;
#pragma unroll
  for (int mf = 0; mf < 4; ++mf) {
#pragma unroll
    for (int ns = 0; ns < 2; ++ns) {
      int n = n0g + wn * 32 + ns * 16 + colq;
      float vbf = bf_[n], vbi = bi_[n], vbo = bo_[n], vbc = bc_[n];
#pragma unroll
      for (int r = 0; r < 4; ++r) {
        int row = b0 + wm * 64 + mf * 16 + rq * 4 + r;
        float fg = sigmoidf_(acc[mf][0 + ns][r] + vbf);
        float ig = sigmoidf_(acc[mf][2 + ns][r] + vbi);
        float og = sigmoidf_(acc[mf][4 + ns][r] + vbo);
        float cg = tanhf_  (acc[mf][6 + ns][r] + vbc);
        float cp = Cp[(size_t)row * H_SZ + n];
        float Ct = fg * cp + ig * cg;
        float ht = og * tanhf_(Ct);
        outh[(size_t)row * H_SZ + n] = ht;
        outC[(size_t)row * H_SZ + n] = Ct;
      }
    }
  }
#undef STAGE_A
#undef STAGE_W
#undef RD_A
#undef RD_B
#undef MFQ
#undef BAR
#undef VMC6
}

extern "C" void kernel_launch(void* const* d_in, const int* in_sizes, int n_in,
                              void* d_out, int out_size, void* d_ws, size_t ws_size,
                              hipStream_t stream) {
  const float* x  = (const float*)d_in[0];
  const float* hp = (const float*)d_in[1];
  const float* Cp = (const float*)d_in[2];
  const float* Wf = (const float*)d_in[3];
  const float* bf = (const float*)d_in[4];
  const float* Wi = (const float*)d_in[5];
  const float* bi = (const float*)d_in[6];
  const float* Wc = (const float*)d_in[7];
  const float* bc = (const float*)d_in[8];
  const float* Wo = (const float*)d_in[9];
  const float* bo = (const float*)d_in[10];

  ushort* Wt  = (ushort*)d_ws;                           // 16 MiB
  ushort* Abf = (ushort*)((char*)d_ws + (16u << 20));    // 32 MiB

  dim3 gridT(16, 32, 4);
  convert_w_kernel<<<gridT, 256, 0, stream>>>(Wf, Wi, Wo, Wc, Wt);
  convert_a_kernel<<<8192, 256, 0, stream>>>(x, hp, Abf);

  lstm_fused_kernel<<<512, 512, 0, stream>>>(Cp, Wt, Abf,
                                             bf, bi, bo, bc, (float*)d_out);
}

// Round 8
// 157.821 us; speedup vs baseline: 2.2572x; 1.0043x over previous
//
#include <hip/hip_runtime.h>
#include <hip/hip_bf16.h>

#define B_SZ 8192
#define IH   2048
#define H_SZ 1024
#define BM   256            // rows per block
#define BK   64             // K per tile
#define NT   (IH / BK)      // 32 K-tiles
#define NI   (NT / 2)       // 16 iterations, 2 K-tiles each
#define DBUF 65536          // one dbuf: A [256][128B] + W [256][128B]
#define WOFF 32768          // W region offset inside a dbuf

typedef __attribute__((ext_vector_type(8))) short  short8;
typedef __attribute__((ext_vector_type(4))) float  floatx4;

static __device__ __forceinline__ ushort f2bf(float f) {
  union { float f; unsigned u; } v; v.f = f;
  unsigned u = v.u;
  u += 0x7fffu + ((u >> 16) & 1u);   // RNE
  return (ushort)(u >> 16);
}
static __device__ __forceinline__ float sigmoidf_(float x) {
  return 1.0f / (1.0f + __expf(-x));
}
static __device__ __forceinline__ float tanhf_(float x) {
  float ax = fabsf(x);
  float e = __expf(-2.0f * ax);
  float t = (1.0f - e) / (1.0f + e);
  return copysignf(t, x);
}
static __device__ __forceinline__ void gload_lds16(const void* gsrc, void* ldst) {
  __builtin_amdgcn_global_load_lds(
      (__attribute__((address_space(1))) const void*)gsrc,
      (__attribute__((address_space(3))) void*)ldst, 16, 0, 0);
}

// ---------------------------------------------------------------------------
// Pre-pass 1: W[k][n] fp32 -> Wt[g][n][k] bf16 (K-contiguous for MFMA B-frag)
// ---------------------------------------------------------------------------
__global__ __launch_bounds__(256) void convert_w_kernel(
    const float* __restrict__ Wf, const float* __restrict__ Wi,
    const float* __restrict__ Wo, const float* __restrict__ Wc,
    ushort* __restrict__ Wt) {
  __shared__ float tile[64][65];
  const int g  = blockIdx.z;
  const float* W = (g == 0) ? Wf : (g == 1) ? Wi : (g == 2) ? Wo : Wc;
  const int n0 = blockIdx.x * 64;
  const int k0 = blockIdx.y * 64;
  const int tid = threadIdx.x;
#pragma unroll
  for (int i = 0; i < 4; ++i) {
    int c = i * 256 + tid;
    int r = c >> 4, c4 = c & 15;
    float4 v = *(const float4*)(W + (size_t)(k0 + r) * H_SZ + n0 + c4 * 4);
    tile[r][c4 * 4 + 0] = v.x;
    tile[r][c4 * 4 + 1] = v.y;
    tile[r][c4 * 4 + 2] = v.z;
    tile[r][c4 * 4 + 3] = v.w;
  }
  __syncthreads();
  const int n  = tid >> 2;
  const int kc = (tid & 3) * 16;
  ushort o[16] __attribute__((aligned(16)));
#pragma unroll
  for (int e = 0; e < 16; ++e) o[e] = f2bf(tile[kc + e][n]);
  ushort* dst = Wt + ((size_t)g * H_SZ + n0 + n) * IH + k0 + kc;
  *(uint4*)(dst)     = *(uint4*)&o[0];
  *(uint4*)(dst + 8) = *(uint4*)&o[8];
}

// ---------------------------------------------------------------------------
// Pre-pass 2: A = [x | h_prev] fp32 -> Abf[8192][2048] bf16
// ---------------------------------------------------------------------------
__global__ __launch_bounds__(256) void convert_a_kernel(
    const float* __restrict__ x, const float* __restrict__ hp,
    ushort* __restrict__ Abf) {
  size_t idx = ((size_t)blockIdx.x * 256 + threadIdx.x) * 8;
  size_t row = idx >> 11;
  size_t col = idx & 2047;
  const float* src = (col < 1024) ? (x  + row * 1024 + col)
                                  : (hp + row * 1024 + (col - 1024));
  float4 v0 = *(const float4*)(src);
  float4 v1 = *(const float4*)(src + 4);
  ushort o[8] __attribute__((aligned(16)));
  o[0] = f2bf(v0.x); o[1] = f2bf(v0.y); o[2] = f2bf(v0.z); o[3] = f2bf(v0.w);
  o[4] = f2bf(v1.x); o[5] = f2bf(v1.y); o[6] = f2bf(v1.z); o[7] = f2bf(v1.w);
  *(uint4*)(Abf + idx) = *(uint4*)&o[0];
}

// ---------------------------------------------------------------------------
// Fused 4-gate GEMM + LSTM epilogue — 4-phase/iter schedule (halved barrier
// windows vs r4-r7's 8-phase; per-iter: 8 barriers not 16).
//
// Per K-tile, 2 phases:
//   Ph_a: read aF all (8 b128) + bF j0-3 (8); MFMA mf0-3 x j0-3 x k0-1 (32)
//   Ph_b: read bF j4-7 (8);                  MFMA mf0-3 x j4-7 x k0-1 (32)
//
// Stage slots (2 gloads per STAGE):
//   P1{d1.W1@t1}  P2{d0.W0@t2, d0.A0}  P3{d0.A1, d0.W1}  P4{d1.W0@t3, A0, A1}
// Same-phase disjointness (stage target vs this phase's reads):
//   P1 reads d0.A+W0, stages d1.W1 (other dbuf)          OK
//   P2 reads d0.W1(j4-7), stages d0.W0 + d0.A            OK (disjoint regions)
//   P3 reads d1.A+W0, stages d0.*                        OK
//   P4 reads d1.W1, stages d1.W0 + d1.A                  OK
// WAR (region's prior readers retired >=1 barrier before stage issue):
//   d1.W1: read prev-P4, staged P1         d0.W0/A0: read P1, staged P2
//   d0.A1: read P1, staged P3  d0.W1: read P2, staged P3
//   d1.W0/A0/A1: read P3, staged P4        -- all hold.
// RAW (tile fully landed before reads):
//   d1 = {prevP4: W0,A0,A1} + {P1: W1}; VMC(4) end-P2 retires through P1
//     (outstanding: prevP4=6, P1=2, P2=4 -> allow newest 4) => d1 ready < P3.
//   d0' = {P2: W0,A0} + {P3: A1,W1}; VMC(6) end-P4 retires through P3
//     (outstanding: P3=4, P4=6 -> allow newest 6) => d0' ready < next-P1.
// Landing-late check: each stage's write lands no earlier than its issue
//   (>= 1 barrier after the region's readers) and is vmcnt-retired before
//   the region's next readers -- both directions covered above.
// No explicit lgkm: every fragment is consumed by an MFMA in its own (or
//   next, for aF) phase; compiler inserts counted lgkmcnt before consumers.
// ---------------------------------------------------------------------------
__global__ __launch_bounds__(512, 2) void lstm_fused_kernel(
    const float* __restrict__ Cp, const ushort* __restrict__ Wt,
    const ushort* __restrict__ Abf,
    const float* __restrict__ bf_, const float* __restrict__ bi_,
    const float* __restrict__ bo_, const float* __restrict__ bc_,
    float* __restrict__ out) {
  __shared__ char lds[2 * DBUF];   // 128 KiB

  const int bid = blockIdx.x;
  const int wg  = (bid & 7) * 64 + (bid >> 3);   // bijective, 512 % 8 == 0
  const int b0  = (wg >> 4) * BM;                // 32 M-tiles
  const int n0g = (wg & 15) * 64;                // 16 N-tiles (64 cols/gate)

  const int tid = threadIdx.x;
  const int ln  = tid & 63;
  const int wv  = tid >> 6;
  const int wm  = wv >> 1, wn = wv & 1;

  floatx4 acc[4][8];
#pragma unroll
  for (int m = 0; m < 4; ++m)
#pragma unroll
    for (int j = 0; j < 8; ++j) acc[m][j] = {0.f, 0.f, 0.f, 0.f};

  // ---- pinned ds_read bases ----
  const int sw  = (ln & 7) << 4;
  const int kb0 = (((ln >> 4) << 4)) ^ sw;
  const int kb1 = (64 + ((ln >> 4) << 4)) ^ sw;
  const int aR  = (wm * 64 + (ln & 15)) * 128;
  const int bR  = WOFF + (wn * 32 + (ln & 15)) * 128;
  int aB0[2], aB1[2], bB0[2], bB1[2];
#pragma unroll
  for (int d = 0; d < 2; ++d) {
    aB0[d] = d * DBUF + aR + kb0;  aB1[d] = d * DBUF + aR + kb1;
    bB0[d] = d * DBUF + bR + kb0;  bB1[d] = d * DBUF + bR + kb1;
  }

  // ---- stage constants (32-bit offsets; Abf 32 MiB, Wt 16 MiB) ----
  const unsigned kcsw = ((tid & 7) * 16) ^ (((tid >> 3) & 7) << 4);
  const char*  AbfB = (const char*)Abf;
  const char*  WtB  = (const char*)Wt;
  unsigned aoff[2];
#pragma unroll
  for (int i = 0; i < 2; ++i)
    aoff[i] = ((unsigned)(b0 + i * 64 + (tid >> 3)) << 12) + kcsw;
  unsigned woff[2][2];
#pragma unroll
  for (int h = 0; h < 2; ++h)
#pragma unroll
    for (int i = 0; i < 2; ++i) {
      int nrt  = h * 128 + i * 64 + (tid >> 3);
      int g    = nrt >> 6, nloc = nrt & 63;
      woff[h][i] = ((unsigned)(g * H_SZ + n0g + nloc) << 12) + kcsw;
    }
  int dsto[2];
#pragma unroll
  for (int i = 0; i < 2; ++i) dsto[i] = (i * 512 + wv * 64) * 16;

#define STAGE_A(db, ktb, h)                                                   \
  do {                                                                        \
    gload_lds16(AbfB + (aoff[0] + ((unsigned)(h) << 19) + (unsigned)(ktb)),   \
                lds + (db) + (h) * 16384 + dsto[0]);                          \
    gload_lds16(AbfB + (aoff[1] + ((unsigned)(h) << 19) + (unsigned)(ktb)),   \
                lds + (db) + (h) * 16384 + dsto[1]);                          \
  } while (0)
#define STAGE_W(db, ktb, h)                                                   \
  do {                                                                        \
    gload_lds16(WtB + (woff[h][0] + (unsigned)(ktb)),                         \
                lds + (db) + WOFF + (h) * 16384 + dsto[0]);                   \
    gload_lds16(WtB + (woff[h][1] + (unsigned)(ktb)),                         \
                lds + (db) + WOFF + (h) * 16384 + dsto[1]);                   \
  } while (0)

  short8 aF[4][2];
  short8 bF[8][2];
#define RD_A(dbi, mf)                                                         \
  do {                                                                        \
    aF[mf][0] = *(const short8*)(lds + aB0[dbi] + (mf) * 2048);               \
    aF[mf][1] = *(const short8*)(lds + aB1[dbi] + (mf) * 2048);               \
  } while (0)
#define RD_B(dbi, j)                                                          \
  do {                                                                        \
    bF[j][0] = *(const short8*)(lds + bB0[dbi] + ((j) >> 1) * 8192 +          \
                                ((j) & 1) * 2048);                            \
    bF[j][1] = *(const short8*)(lds + bB1[dbi] + ((j) >> 1) * 8192 +          \
                                ((j) & 1) * 2048);                            \
  } while (0)
#define RDQA(d)  do { RD_A(d, 0); RD_A(d, 1); RD_A(d, 2); RD_A(d, 3); } while (0)
#define RDB03(d) do { RD_B(d, 0); RD_B(d, 1); RD_B(d, 2); RD_B(d, 3); } while (0)
#define RDB47(d) do { RD_B(d, 4); RD_B(d, 5); RD_B(d, 6); RD_B(d, 7); } while (0)
// 32 MFMA: k outer, mf mid, j inner -> no back-to-back same-acc.
#define MFQ(jh)                                                               \
  do {                                                                        \
    __builtin_amdgcn_s_setprio(1);                                            \
    _Pragma("unroll")                                                         \
    for (int k_ = 0; k_ < 2; ++k_)                                            \
      _Pragma("unroll")                                                       \
      for (int mf_ = 0; mf_ < 4; ++mf_)                                       \
        _Pragma("unroll")                                                     \
        for (int j_ = 4 * (jh); j_ < 4 * (jh) + 4; ++j_)                      \
          acc[mf_][j_] = __builtin_amdgcn_mfma_f32_16x16x32_bf16(             \
              aF[mf_][k_], bF[j_][k_], acc[mf_][j_], 0, 0, 0);                \
    __builtin_amdgcn_s_setprio(0);                                            \
  } while (0)
#define BAR   __builtin_amdgcn_s_barrier()
#define VMC(n) asm volatile("s_waitcnt vmcnt(" #n ")" ::: "memory")

  // ---- prologue: d0 full (8 gloads) + d1 {W0,A0,A1} (6); wait d0 ----
  STAGE_W(0, 0, 0); STAGE_A(0, 0, 0); STAGE_A(0, 0, 1); STAGE_W(0, 0, 1);
  STAGE_W(DBUF, 128, 0); STAGE_A(DBUF, 128, 0); STAGE_A(DBUF, 128, 1);
  VMC(6);
  BAR;

#pragma unroll 1
  for (int it = 0; it < NI; ++it) {
    const int kt1b  = (2 * it + 1) * 128;
    const int ktn0b = ((2 * it + 2) & 31) * 128;
    const int ktn1b = ((2 * it + 3) & 31) * 128;
    // P1: d0 Ph_a
    RDQA(0); RDB03(0);
    STAGE_W(DBUF, kt1b, 1);
    BAR; MFQ(0); BAR;
    // P2: d0 Ph_b; vmcnt(4) => d1 fully landed
    RDB47(0);
    STAGE_W(0, ktn0b, 0); STAGE_A(0, ktn0b, 0);
    BAR; MFQ(1); VMC(4); BAR;
    // P3: d1 Ph_a
    RDQA(1); RDB03(1);
    STAGE_A(0, ktn0b, 1); STAGE_W(0, ktn0b, 1);
    BAR; MFQ(0); BAR;
    // P4: d1 Ph_b; vmcnt(6) => d0' fully landed
    RDB47(1);
    STAGE_W(DBUF, ktn1b, 0); STAGE_A(DBUF, ktn1b, 0); STAGE_A(DBUF, ktn1b, 1);
    BAR; MFQ(1); VMC(6); BAR;
  }

  // ---- epilogue: gate g at acc[mf][2g+ns]; same lane/reg across gates ----
  const int colq = ln & 15;
  const int rq   = ln >> 4;
  float* outh = out;
  float* outC = out + (size_t)B_SZ * H_SZ;
#pragma unroll
  for (int mf = 0; mf < 4; ++mf) {
#pragma unroll
    for (int ns = 0; ns < 2; ++ns) {
      int n = n0g + wn * 32 + ns * 16 + colq;
      float vbf = bf_[n], vbi = bi_[n], vbo = bo_[n], vbc = bc_[n];
#pragma unroll
      for (int r = 0; r < 4; ++r) {
        int row = b0 + wm * 64 + mf * 16 + rq * 4 + r;
        float fg = sigmoidf_(acc[mf][0 + ns][r] + vbf);
        float ig = sigmoidf_(acc[mf][2 + ns][r] + vbi);
        float og = sigmoidf_(acc[mf][4 + ns][r] + vbo);
        float cg = tanhf_  (acc[mf][6 + ns][r] + vbc);
        float cp = Cp[(size_t)row * H_SZ + n];
        float Ct = fg * cp + ig * cg;
        float ht = og * tanhf_(Ct);
        outh[(size_t)row * H_SZ + n] = ht;
        outC[(size_t)row * H_SZ + n] = Ct;
      }
    }
  }
#undef STAGE_A
#undef STAGE_W
#undef RD_A
#undef RD_B
#undef RDQA
#undef RDB03
#undef RDB47
#undef MFQ
#undef BAR
#undef VMC
}

extern "C" void kernel_launch(void* const* d_in, const int* in_sizes, int n_in,
                              void* d_out, int out_size, void* d_ws, size_t ws_size,
                              hipStream_t stream) {
  const float* x  = (const float*)d_in[0];
  const float* hp = (const float*)d_in[1];
  const float* Cp = (const float*)d_in[2];
  const float* Wf = (const float*)d_in[3];
  const float* bf = (const float*)d_in[4];
  const float* Wi = (const float*)d_in[5];
  const float* bi = (const float*)d_in[6];
  const float* Wc = (const float*)d_in[7];
  const float* bc = (const float*)d_in[8];
  const float* Wo = (const float*)d_in[9];
  const float* bo = (const float*)d_in[10];

  ushort* Wt  = (ushort*)d_ws;                           // 16 MiB
  ushort* Abf = (ushort*)((char*)d_ws + (16u << 20));    // 32 MiB

  dim3 gridT(16, 32, 4);
  convert_w_kernel<<<gridT, 256, 0, stream>>>(Wf, Wi, Wo, Wc, Wt);
  convert_a_kernel<<<8192, 256, 0, stream>>>(x, hp, Abf);

  lstm_fused_kernel<<<512, 512, 0, stream>>>(Cp, Wt, Abf,
                                             bf, bi, bo, bc, (float*)d_out);
}